// Round 3
// baseline (346.820 us; speedup 1.0000x reference)
//
#include <hip/hip_runtime.h>
#include <math.h>

#define SUBS 20
#define TAPS 201
#define ENO 2000
#define INO 500
#define TDATA 20000

typedef __bf16 bf16x8 __attribute__((ext_vector_type(8)));
typedef float f32x4 __attribute__((ext_vector_type(4)));

#define WGE_STRIDE 2048
#define WGI_STRIDE 512

// workspace byte offsets (ws is ~640 MB per fill counter; 29.2 MB used)
#define WGE_OFF  0ull                    // ushort[64*2048] bf16 weights (E)
#define WGI_OFF  262144ull               // ushort[64*512]  bf16 weights (I)
#define KERN_OFF 327680ull               // float[40*201]   synapse kernels
#define INE_OFF  360448ull               // float[60*20000] E partial chunk0
#define INI_OFF  (INE_OFF + 4800000ull)  // float[60*20000] I (full K)
#define P1_OFF   (INI_OFF + 4800000ull)  // float[60*20000] E partial chunk1
#define P2_OFF   (P1_OFF  + 4800000ull)  // float[60*20000] E partial chunk2
#define P3_OFF   (P2_OFF  + 4800000ull)  // float[60*20000] E partial chunk3
#define SYN_OFF  (P3_OFF  + 4800000ull)  // float[60*20000] syn_in (no alias)

__device__ __forceinline__ unsigned short f2bf(float f) {
  union { float f; unsigned int u; } c; c.f = f;
  unsigned int u = c.u;
  return (unsigned short)((u + 0x7FFFu + ((u >> 16) & 1u)) >> 16);  // RTNE
}

__device__ __forceinline__ float fast_tanh(float x) {
  const float ax = fabsf(x);
  const float e  = __expf(2.f * ax);     // e=inf -> t=1 (saturation) is exact
  const float t  = 1.f - 2.f / (e + 1.f);
  return copysignf(t, x);
}

// ---------------------------------------------------------------------------
// K1: per-column prep (theta, hard/soft/softb) + kern filters + weight pads
// ---------------------------------------------------------------------------
__global__ __launch_bounds__(256) void prep_kernel(
    const float* __restrict__ u, const float* __restrict__ v,
    const float* __restrict__ C_log, const float* __restrict__ W_syn,
    const float* __restrict__ Tau_syn, const float* __restrict__ Delta_syn,
    float* __restrict__ out,
    unsigned short* __restrict__ wge, unsigned short* __restrict__ wgi,
    float* __restrict__ kern)
{
  if (blockIdx.x < 10) {
    const int n = blockIdx.x * 256 + threadIdx.x;
    if (n >= 2500) return;
    float x[SUBS], theta[SUBS], rebar[SUBS];
    float mx = -1e30f;
#pragma unroll
    for (int s = 0; s < SUBS; ++s) { x[s] = C_log[s*2500 + n]; mx = fmaxf(mx, x[s]); }
    float sum = 0.f;
#pragma unroll
    for (int s = 0; s < SUBS; ++s) { theta[s] = __expf(x[s] - mx); sum += theta[s]; }
    const float inv = 1.f / sum;
    int idx = 0; float best = -1e30f;
#pragma unroll
    for (int s = 0; s < SUBS; ++s) {
      theta[s] *= inv;
      out[60000 + s*2500 + n] = theta[s];
      const float uu = u[s*2500 + n];
      const float r = __logf(theta[s]) - __logf(-__logf(uu));
      rebar[s] = r;
      if (r > best) { best = r; idx = s; }   // first-wins strict >
    }
    const float lvk = __logf(v[idx*2500 + n]);
#pragma unroll
    for (int s = 0; s < SUBS; ++s) {
      const float hz = (s == idx) ? 1.f : 0.f;
      const float sz = 1.f / (1.f + __expf(-2.f * rebar[s])) + 1e-9f;
      const float vv = v[s*2500 + n];
      const float zb = (s == idx) ? (-__logf(-__logf(vv)))
                                  : (-__logf(-__logf(vv) / theta[s] - lvk));
      const float szb = 1.f / (1.f + __expf(-2.f * zb)) + 1e-9f;
      out[110000 + s*2500 + n] = hz;
      out[160000 + s*2500 + n] = sz;
      out[210000 + s*2500 + n] = szb;
      if (n < ENO) {
        wge[(s     )*WGE_STRIDE + n] = f2bf(hz);
        wge[(20 + s)*WGE_STRIDE + n] = f2bf(sz);
        wge[(40 + s)*WGE_STRIDE + n] = f2bf(szb);
      } else {
        const int k = n - ENO;
        wgi[(s     )*WGI_STRIDE + k] = f2bf(hz);
        wgi[(20 + s)*WGI_STRIDE + k] = f2bf(sz);
        wgi[(40 + s)*WGI_STRIDE + k] = f2bf(szb);
      }
    }
  } else {
    const int tid = threadIdx.x;
    for (int i = tid; i < 40*TAPS; i += 256) {
      const int ch = i / TAPS, m = i - ch*TAPS;
      const float dl  = __expf(Delta_syn[ch]);
      const float tau = __expf(Tau_syn[ch]);
      const float t  = fmaxf((float)m - dl, 0.f);
      const float tt = t / tau;
      kern[i] = tt * __expf(-tt) * W_syn[ch];
    }
    // zero the padded weight regions (ws is poisoned 0xAA every launch)
    for (int i = tid; i < 4*2048; i += 256) wge[(60 + (i >> 11))*WGE_STRIDE + (i & 2047)] = 0;
    for (int i = tid; i < 60*48;  i += 256) wge[(i / 48)*WGE_STRIDE + 2000 + (i % 48)] = 0;
    for (int i = tid; i < 4*512;  i += 256) wgi[(60 + (i >> 9))*WGI_STRIDE + (i & 511)] = 0;
    for (int i = tid; i < 60*12;  i += 256) wgi[(i / 12)*WGI_STRIDE + 500 + (i % 12)] = 0;
  }
}

// ---------------------------------------------------------------------------
// K2: bf16 MFMA GEMM — wave-autonomous, BARRIER-FREE, LDS double-buffered.
//     Each wave owns 16 t-rows x 64 channels and stages its own A tile into
//     wave-private LDS (same-wave ds_write->ds_read needs only lgkmcnt, so
//     zero __syncthreads -> no vmcnt(0) drains anywhere).
//     Pipeline per 64-k step: issue coalesced A loads for st+1 (4x float4 per
//     lane = 4KB/wave in flight) -> compute st (B frags direct from L2 + LDS
//     A frags) -> cvt+ds_write st+1. Loads overlap the full compute phase.
//     grid = (313, 5); y: 0..3 = E k-quarters -> {in_e,P1,P2,P3}; 4 = I full.
//     K-tail: 4-granular address clamp (in-bounds since K%4==0); misplaced A
//     values only ever multiply zero-padded B columns.
// ---------------------------------------------------------------------------
__global__ __launch_bounds__(256) void gemm_kernel(
    const float* __restrict__ S_e, const float* __restrict__ S_i,
    const unsigned short* __restrict__ wge, const unsigned short* __restrict__ wgi,
    float* __restrict__ in_e, float* __restrict__ in_i,
    float* __restrict__ P1, float* __restrict__ P2, float* __restrict__ P3)
{
  // [wave][dbuf][16 rows * 72 stride] bf16 -> 4*2*1152*2B = 18.4 KB
  __shared__ unsigned short Alds[4][2][16*72];
  const int tid  = threadIdx.x;
  const int wave = tid >> 6;
  const int lane = tid & 63;
  const int m16  = lane & 15;
  const int quad = lane >> 4;
  const int rr   = lane >> 2;          // staging row 0..15
  const int s4   = lane & 3;           // staging slot (col group)
  const int t0   = blockIdx.x * 64;
  const int cy   = blockIdx.y;
  const bool isE = (cy < 4);

  const float* S = isE ? S_e : S_i;
  const unsigned short* Wg = isE ? wge : wgi;
  float* outp = (cy == 0) ? in_e : (cy == 1) ? P1 : (cy == 2) ? P2
              : (cy == 3) ? P3   : in_i;
  const int K       = isE ? ENO : INO;
  const int Wstride = isE ? WGE_STRIDE : WGI_STRIDE;
  const int k_base  = isE ? cy * 512 : 0;

  // A staging: this lane loads row rr of the wave's 16, cols s4*4 + j*16.
  // Per instruction: lanes 0-3 cover 64B contiguous of one row (coalesced).
  const int tA = t0 + wave*16 + rr;
  const float* Arow = S + (size_t)((tA < TDATA) ? tA : TDATA - 1) * K;

  // B fragment row pointers (channel rows j*16 + m16), zero-padded buffers
  const unsigned short* B0 = Wg + (size_t)(m16     ) * Wstride;
  const unsigned short* B1 = Wg + (size_t)(m16 + 16) * Wstride;
  const unsigned short* B2 = Wg + (size_t)(m16 + 32) * Wstride;
  const unsigned short* B3 = Wg + (size_t)(m16 + 48) * Wstride;

  f32x4 acc0 = {0.f,0.f,0.f,0.f};
  f32x4 acc1 = acc0, acc2 = acc0, acc3 = acc0;

#define LDA(st, d0, d1, d2, d3) do {                                  \
    const int cb_ = k_base + (st)*64 + s4*4;                          \
    const int c0_ = (cb_      <= K-4) ? cb_      : K-4;               \
    const int c1_ = (cb_ + 16 <= K-4) ? cb_ + 16 : K-4;               \
    const int c2_ = (cb_ + 32 <= K-4) ? cb_ + 32 : K-4;               \
    const int c3_ = (cb_ + 48 <= K-4) ? cb_ + 48 : K-4;               \
    d0 = *(const float4*)(Arow + c0_);                                \
    d1 = *(const float4*)(Arow + c1_);                                \
    d2 = *(const float4*)(Arow + c2_);                                \
    d3 = *(const float4*)(Arow + c3_);                                \
  } while (0)

#define STW(d, f0_, f1_, f2_, f3_) do {                               \
    unsigned short* w_ = &Alds[wave][d][rr*72 + s4*4];                \
    ushort4 q_;                                                       \
    q_.x=f2bf(f0_.x); q_.y=f2bf(f0_.y); q_.z=f2bf(f0_.z); q_.w=f2bf(f0_.w); \
    *(ushort4*)(w_     ) = q_;                                        \
    q_.x=f2bf(f1_.x); q_.y=f2bf(f1_.y); q_.z=f2bf(f1_.z); q_.w=f2bf(f1_.w); \
    *(ushort4*)(w_ + 16) = q_;                                        \
    q_.x=f2bf(f2_.x); q_.y=f2bf(f2_.y); q_.z=f2bf(f2_.z); q_.w=f2bf(f2_.w); \
    *(ushort4*)(w_ + 32) = q_;                                        \
    q_.x=f2bf(f3_.x); q_.y=f2bf(f3_.y); q_.z=f2bf(f3_.z); q_.w=f2bf(f3_.w); \
    *(ushort4*)(w_ + 48) = q_;                                        \
  } while (0)

  // prologue: stage step 0
  {
    float4 f0, f1, f2, f3;
    LDA(0, f0, f1, f2, f3);
    STW(0, f0, f1, f2, f3);
  }

#pragma unroll
  for (int st = 0; st < 8; ++st) {
    // phase 1: issue next step's coalesced A loads (fly across the MFMAs;
    // no barrier exists to force a drain)
    float4 n0, n1, n2, n3;
    if (st < 7) LDA(st + 1, n0, n1, n2, n3);
    // phase 2: compute step st from buf (st&1)
    const unsigned short* bufc = &Alds[wave][st & 1][0];
#pragma unroll
    for (int h = 0; h < 2; ++h) {
      const int kh = k_base + st*64 + h*32 + quad*8;
      const bf16x8 b0 = *(const bf16x8*)(B0 + kh);
      const bf16x8 b1 = *(const bf16x8*)(B1 + kh);
      const bf16x8 b2 = *(const bf16x8*)(B2 + kh);
      const bf16x8 b3 = *(const bf16x8*)(B3 + kh);
      const bf16x8 a  = *(const bf16x8*)(bufc + m16*72 + h*32 + quad*8);
      acc0 = __builtin_amdgcn_mfma_f32_16x16x32_bf16(a, b0, acc0, 0, 0, 0);
      acc1 = __builtin_amdgcn_mfma_f32_16x16x32_bf16(a, b1, acc1, 0, 0, 0);
      acc2 = __builtin_amdgcn_mfma_f32_16x16x32_bf16(a, b2, acc2, 0, 0, 0);
      acc3 = __builtin_amdgcn_mfma_f32_16x16x32_bf16(a, b3, acc3, 0, 0, 0);
    }
    // phase 3: convert + stage step st+1 (vmcnt wait lands here, after MFMAs)
    if (st < 7) STW((st + 1) & 1, n0, n1, n2, n3);
  }
#undef LDA
#undef STW

  // epilogue: C/D layout col=m16 -> channel, row=quad*4+r -> t-local
  const int t = t0 + wave*16 + quad*4;
  if (t < TDATA) {
    float* o = outp + t;
    *(float4*)(o + (size_t)(     m16)*TDATA) = *(float4*)&acc0;
    *(float4*)(o + (size_t)(16 + m16)*TDATA) = *(float4*)&acc1;
    *(float4*)(o + (size_t)(32 + m16)*TDATA) = *(float4*)&acc2;
    if (m16 < 12)
      *(float4*)(o + (size_t)(48 + m16)*TDATA) = *(float4*)&acc3;
  }
}

// ---------------------------------------------------------------------------
// K3: 201-tap causal FIR per (var,s), with the split-K reduction fused into
//     the LDS staging: E window = in_e + P1 + P2 + P3, I window = in_i.
// ---------------------------------------------------------------------------
__device__ __forceinline__ int swz(int i) { return i + (i >> 5); }

__global__ __launch_bounds__(256) void conv_kernel(
    const float* __restrict__ in_e, const float* __restrict__ P1,
    const float* __restrict__ P2,  const float* __restrict__ P3,
    const float* __restrict__ in_i,
    const float* __restrict__ kern, float* __restrict__ syn)
{
  __shared__ float Ee[2320];
  __shared__ float Ei[2320];
  const int ch = blockIdx.y;            // var*20 + s
  const int t0 = blockIdx.x * 2048;
  const int s  = ch % SUBS;
  const size_t off = (size_t)ch * TDATA;
  for (int i = threadIdx.x; i < 2248; i += 256) {
    const int g = t0 - 200 + i;
    float e = 0.f, ii = 0.f;
    if (g >= 0 && g < TDATA) {
      e = in_e[off + g] + P1[off + g] + P2[off + g] + P3[off + g];
      ii = in_i[off + g];
    }
    Ee[swz(i)] = e;
    Ei[swz(i)] = ii;
  }
  __syncthreads();
  const float* ke = kern + (size_t)(s*2    ) * TAPS;
  const float* ki = kern + (size_t)(s*2 + 1) * TAPS;
  const int tb = threadIdx.x * 8;
  float acc[8] = {0.f,0.f,0.f,0.f,0.f,0.f,0.f,0.f};
  float we[8], wi[8];
#pragma unroll
  for (int j = 0; j < 8; ++j) {
    we[j] = Ee[swz(tb + 200 + j)];
    wi[j] = Ei[swz(tb + 200 + j)];
  }
#pragma unroll 8
  for (int m = 0; m < TAPS; ++m) {
    const float k0 = ke[m];
    const float k1 = ki[m];
#pragma unroll
    for (int j = 0; j < 8; ++j)
      acc[j] = fmaf(we[j], k0, fmaf(wi[j], k1, acc[j]));
    if (m < TAPS - 1) {
#pragma unroll
      for (int j = 7; j > 0; --j) { we[j] = we[j-1]; wi[j] = wi[j-1]; }
      we[0] = Ee[swz(tb + 199 - m)];
      wi[0] = Ei[swz(tb + 199 - m)];
    }
  }
  const int t = t0 + tb;
  if (t < TDATA) {
    float* o = syn + off + t;
    *(float4*)(o    ) = make_float4(acc[0], acc[1], acc[2], acc[3]);
    *(float4*)(o + 4) = make_float4(acc[4], acc[5], acc[6], acc[7]);
  }
}

// ---------------------------------------------------------------------------
// K4: tanh tree combine -> V outputs
// ---------------------------------------------------------------------------
__global__ __launch_bounds__(256) void tree_kernel(
    const float* __restrict__ syn, const float* __restrict__ W_sub,
    const float* __restrict__ V_o, float* __restrict__ out)
{
  const int t = blockIdx.x * 256 + threadIdx.x;
  const int var = blockIdx.y;
  if (t >= TDATA) return;
  const float* sp = syn + (size_t)var * SUBS * TDATA + t;
  float so[SUBS];
#pragma unroll
  for (int s = SUBS - 1; s >= 0; --s) {
    float val = sp[(size_t)s * TDATA];
    const int c1 = 2*s + 1, c2 = 2*s + 2;
    if (c1 < SUBS) val += so[c1] * W_sub[c1];
    if (c2 < SUBS) val += so[c2] * W_sub[c2];
    so[s] = fast_tanh(val);
  }
  out[(size_t)var * TDATA + t] = so[0] * W_sub[0] + V_o[0];
}

extern "C" void kernel_launch(void* const* d_in, const int* in_sizes, int n_in,
                              void* d_out, int out_size, void* d_ws, size_t ws_size,
                              hipStream_t stream) {
  const float* S_e     = (const float*)d_in[0];
  const float* S_i     = (const float*)d_in[1];
  const float* u       = (const float*)d_in[2];
  const float* v       = (const float*)d_in[3];
  const float* W_syn   = (const float*)d_in[4];
  const float* Tau_syn = (const float*)d_in[5];
  const float* Delta   = (const float*)d_in[6];
  const float* W_sub   = (const float*)d_in[7];
  const float* V_o     = (const float*)d_in[8];
  const float* C_log   = (const float*)d_in[10];   // d_in[9] = Theta, unused
  float* out = (float*)d_out;
  char* ws = (char*)d_ws;
  unsigned short* wge = (unsigned short*)(ws + WGE_OFF);
  unsigned short* wgi = (unsigned short*)(ws + WGI_OFF);
  float* kern = (float*)(ws + KERN_OFF);
  float* in_e = (float*)(ws + INE_OFF);
  float* in_i = (float*)(ws + INI_OFF);
  float* P1   = (float*)(ws + P1_OFF);
  float* P2   = (float*)(ws + P2_OFF);
  float* P3   = (float*)(ws + P3_OFF);
  float* syn  = (float*)(ws + SYN_OFF);

  prep_kernel<<<dim3(11), dim3(256), 0, stream>>>(u, v, C_log, W_syn, Tau_syn,
                                                  Delta, out, wge, wgi, kern);
  gemm_kernel<<<dim3(313, 5), dim3(256), 0, stream>>>(
      S_e, S_i, wge, wgi, in_e, in_i, P1, P2, P3);
  conv_kernel<<<dim3(10, 60), dim3(256), 0, stream>>>(in_e, P1, P2, P3, in_i,
                                                      kern, syn);
  tree_kernel<<<dim3(79, 3), dim3(256), 0, stream>>>(syn, W_sub, V_o, out);
}

// Round 6
// 334.320 us; speedup vs baseline: 1.0374x; 1.0374x over previous
//
#include <hip/hip_runtime.h>
#include <math.h>

#define SUBS 20
#define TAPS 201
#define ENO 2000
#define INO 500
#define TDATA 20000

typedef __bf16 bf16x8 __attribute__((ext_vector_type(8)));
typedef float f32x4 __attribute__((ext_vector_type(4)));

#define WGE_STRIDE 2048
#define WGI_STRIDE 512

// workspace byte offsets (ws is ~640 MB per fill counter; 29.2 MB used)
#define WGE_OFF  0ull                    // ushort[64*2048] bf16 weights (E)
#define WGI_OFF  262144ull               // ushort[64*512]  bf16 weights (I)
#define KERN_OFF 327680ull               // float[40*201]   synapse kernels
#define INE_OFF  360448ull               // float[60*20000] E partial chunk0
#define INI_OFF  (INE_OFF + 4800000ull)  // float[60*20000] I (full K)
#define P1_OFF   (INI_OFF + 4800000ull)  // float[60*20000] E partial chunk1
#define P2_OFF   (P1_OFF  + 4800000ull)  // float[60*20000] E partial chunk2
#define P3_OFF   (P2_OFF  + 4800000ull)  // float[60*20000] E partial chunk3
#define SYN_OFF  (P3_OFF  + 4800000ull)  // float[60*20000] syn_in (no alias)

__device__ __forceinline__ unsigned short f2bf(float f) {
  union { float f; unsigned int u; } c; c.f = f;
  unsigned int u = c.u;
  return (unsigned short)((u + 0x7FFFu + ((u >> 16) & 1u)) >> 16);  // RTNE
}

__device__ __forceinline__ float fast_tanh(float x) {
  const float ax = fabsf(x);
  const float e  = __expf(2.f * ax);     // e=inf -> t=1 (saturation) is exact
  const float t  = 1.f - 2.f / (e + 1.f);
  return copysignf(t, x);
}

// ---------------------------------------------------------------------------
// K1: per-column prep (theta, hard/soft/softb) + kern filters + weight pads
// ---------------------------------------------------------------------------
__global__ __launch_bounds__(256) void prep_kernel(
    const float* __restrict__ u, const float* __restrict__ v,
    const float* __restrict__ C_log, const float* __restrict__ W_syn,
    const float* __restrict__ Tau_syn, const float* __restrict__ Delta_syn,
    float* __restrict__ out,
    unsigned short* __restrict__ wge, unsigned short* __restrict__ wgi,
    float* __restrict__ kern)
{
  if (blockIdx.x < 10) {
    const int n = blockIdx.x * 256 + threadIdx.x;
    if (n >= 2500) return;
    float x[SUBS], theta[SUBS], rebar[SUBS];
    float mx = -1e30f;
#pragma unroll
    for (int s = 0; s < SUBS; ++s) { x[s] = C_log[s*2500 + n]; mx = fmaxf(mx, x[s]); }
    float sum = 0.f;
#pragma unroll
    for (int s = 0; s < SUBS; ++s) { theta[s] = __expf(x[s] - mx); sum += theta[s]; }
    const float inv = 1.f / sum;
    int idx = 0; float best = -1e30f;
#pragma unroll
    for (int s = 0; s < SUBS; ++s) {
      theta[s] *= inv;
      out[60000 + s*2500 + n] = theta[s];
      const float uu = u[s*2500 + n];
      const float r = __logf(theta[s]) - __logf(-__logf(uu));
      rebar[s] = r;
      if (r > best) { best = r; idx = s; }   // first-wins strict >
    }
    const float lvk = __logf(v[idx*2500 + n]);
#pragma unroll
    for (int s = 0; s < SUBS; ++s) {
      const float hz = (s == idx) ? 1.f : 0.f;
      const float sz = 1.f / (1.f + __expf(-2.f * rebar[s])) + 1e-9f;
      const float vv = v[s*2500 + n];
      const float zb = (s == idx) ? (-__logf(-__logf(vv)))
                                  : (-__logf(-__logf(vv) / theta[s] - lvk));
      const float szb = 1.f / (1.f + __expf(-2.f * zb)) + 1e-9f;
      out[110000 + s*2500 + n] = hz;
      out[160000 + s*2500 + n] = sz;
      out[210000 + s*2500 + n] = szb;
      if (n < ENO) {
        wge[(s     )*WGE_STRIDE + n] = f2bf(hz);
        wge[(20 + s)*WGE_STRIDE + n] = f2bf(sz);
        wge[(40 + s)*WGE_STRIDE + n] = f2bf(szb);
      } else {
        const int k = n - ENO;
        wgi[(s     )*WGI_STRIDE + k] = f2bf(hz);
        wgi[(20 + s)*WGI_STRIDE + k] = f2bf(sz);
        wgi[(40 + s)*WGI_STRIDE + k] = f2bf(szb);
      }
    }
  } else {
    const int tid = threadIdx.x;
    for (int i = tid; i < 40*TAPS; i += 256) {
      const int ch = i / TAPS, m = i - ch*TAPS;
      const float dl  = __expf(Delta_syn[ch]);
      const float tau = __expf(Tau_syn[ch]);
      const float t  = fmaxf((float)m - dl, 0.f);
      const float tt = t / tau;
      kern[i] = tt * __expf(-tt) * W_syn[ch];
    }
    // zero the padded weight regions (ws is poisoned 0xAA every launch)
    for (int i = tid; i < 4*2048; i += 256) wge[(60 + (i >> 11))*WGE_STRIDE + (i & 2047)] = 0;
    for (int i = tid; i < 60*48;  i += 256) wge[(i / 48)*WGE_STRIDE + 2000 + (i % 48)] = 0;
    for (int i = tid; i < 4*512;  i += 256) wgi[(60 + (i >> 9))*WGI_STRIDE + (i & 511)] = 0;
    for (int i = tid; i < 60*12;  i += 256) wgi[(i / 12)*WGI_STRIDE + 500 + (i % 12)] = 0;
  }
}

// ---------------------------------------------------------------------------
// K2: bf16 MFMA GEMM — fragment-direct (R2's verified mapping) with
//     INLINE-ASM loads into named registers + explicit counted vmcnt.
//     The compiler cannot sink asm-volatile loads or recycle their dest
//     regs (they are asm outputs consumed later), so each wave holds a
//     true 2-step register double buffer: 12 loads (4x A float4 HBM +
//     8x B frags L2) in flight per step (~12 KB/wave). No LDS, no
//     barriers -> nothing can deadlock; consumers fenced by
//     s_waitcnt vmcnt(N) + sched_barrier(0) (rule #18).
//     grid = (313, 5); y: 0..3 = E k-quarters -> {in_e,P1,P2,P3}; 4 = I.
//     K-tail: A addrs clamped to K-4 (in-bounds, 16B-aligned; misplaced
//     values only meet zero-padded B rows). B reads stay within padded
//     strides (max k+8 = 2048/512 exactly).
// ---------------------------------------------------------------------------
__device__ __forceinline__ void gl16(float4& d, const void* p) {
  asm volatile("global_load_dwordx4 %0, %1, off"
               : "=&v"(d) : "v"(p) : "memory");
}

#define MFMA_B16 __builtin_amdgcn_mfma_f32_16x16x32_bf16
#define BC8(x) __builtin_bit_cast(bf16x8, x)

__global__ __launch_bounds__(256) void gemm_kernel(
    const float* __restrict__ S_e, const float* __restrict__ S_i,
    const unsigned short* __restrict__ wge, const unsigned short* __restrict__ wgi,
    float* __restrict__ in_e, float* __restrict__ in_i,
    float* __restrict__ P1, float* __restrict__ P2, float* __restrict__ P3)
{
  const int tid  = threadIdx.x;
  const int wave = tid >> 6;
  const int lane = tid & 63;
  const int m16  = lane & 15;
  const int quad = lane >> 4;
  const int kq   = quad * 8;
  const int t0   = blockIdx.x * 64;
  const int cy   = blockIdx.y;
  const bool isE = (cy < 4);

  const float* S = isE ? S_e : S_i;
  const unsigned short* Wg = isE ? wge : wgi;
  float* outp = (cy == 0) ? in_e : (cy == 1) ? P1 : (cy == 2) ? P2
              : (cy == 3) ? P3   : in_i;
  const int K       = isE ? ENO : INO;
  const int Wstride = isE ? WGE_STRIDE : WGI_STRIDE;
  const int k_base  = isE ? cy * 512 : 0;

  // A: this lane's t-row (MFMA A frag: row = lane&15, k = quad*8 + j)
  const int tA = t0 + wave*16 + m16;
  const float* Arow = S + (size_t)((tA < TDATA) ? tA : TDATA - 1) * K;
  // B: this lane's 4 channel rows (frag b_j: row = j*16 + (lane&15))
  const unsigned short* B0 = Wg + (size_t)(m16     ) * Wstride;
  const unsigned short* B1 = Wg + (size_t)(m16 + 16) * Wstride;
  const unsigned short* B2 = Wg + (size_t)(m16 + 32) * Wstride;
  const unsigned short* B3 = Wg + (size_t)(m16 + 48) * Wstride;

  f32x4 acc0 = {0.f,0.f,0.f,0.f};
  f32x4 acc1 = acc0, acc2 = acc0, acc3 = acc0;

  // 2-deep register staging (all asm-load targets; compiler must keep live)
  float4 a00,a01,a02,a03, b00,b01,b02,b03,b04,b05,b06,b07;  // set 0
  float4 a10,a11,a12,a13, b10,b11,b12,b13,b14,b15,b16,b17;  // set 1

#define ISSUE(ST, A0,A1,A2,A3, Q0,Q1,Q2,Q3,Q4,Q5,Q6,Q7) do {            \
    const int k0_ = k_base + (ST)*64 + kq;                              \
    const int k1_ = k0_ + 32;                                           \
    gl16(Q0, B0 + k0_); gl16(Q1, B1 + k0_);                             \
    gl16(Q2, B2 + k0_); gl16(Q3, B3 + k0_);                             \
    gl16(Q4, B0 + k1_); gl16(Q5, B1 + k1_);                             \
    gl16(Q6, B2 + k1_); gl16(Q7, B3 + k1_);                             \
    const int c0_ = (k0_     <= K - 4) ? k0_     : K - 4;               \
    const int c1_ = (k0_ + 4 <= K - 4) ? k0_ + 4 : K - 4;               \
    const int c2_ = (k1_     <= K - 4) ? k1_     : K - 4;               \
    const int c3_ = (k1_ + 4 <= K - 4) ? k1_ + 4 : K - 4;               \
    gl16(A0, Arow + c0_); gl16(A1, Arow + c1_);                         \
    gl16(A2, Arow + c2_); gl16(A3, Arow + c3_);                         \
  } while (0)

#define WAITN(N) do {                                                   \
    asm volatile("s_waitcnt vmcnt(" #N ")" ::: "memory");               \
    __builtin_amdgcn_sched_barrier(0);                                  \
  } while (0)

#define COMPUTE(A0,A1,A2,A3, Q0,Q1,Q2,Q3,Q4,Q5,Q6,Q7) do {              \
    bf16x8 x0, x1;                                                      \
    x0[0]=(__bf16)A0.x; x0[1]=(__bf16)A0.y;                             \
    x0[2]=(__bf16)A0.z; x0[3]=(__bf16)A0.w;                             \
    x0[4]=(__bf16)A1.x; x0[5]=(__bf16)A1.y;                             \
    x0[6]=(__bf16)A1.z; x0[7]=(__bf16)A1.w;                             \
    x1[0]=(__bf16)A2.x; x1[1]=(__bf16)A2.y;                             \
    x1[2]=(__bf16)A2.z; x1[3]=(__bf16)A2.w;                             \
    x1[4]=(__bf16)A3.x; x1[5]=(__bf16)A3.y;                             \
    x1[6]=(__bf16)A3.z; x1[7]=(__bf16)A3.w;                             \
    acc0 = MFMA_B16(x0, BC8(Q0), acc0, 0, 0, 0);                        \
    acc1 = MFMA_B16(x0, BC8(Q1), acc1, 0, 0, 0);                        \
    acc2 = MFMA_B16(x0, BC8(Q2), acc2, 0, 0, 0);                        \
    acc3 = MFMA_B16(x0, BC8(Q3), acc3, 0, 0, 0);                        \
    acc0 = MFMA_B16(x1, BC8(Q4), acc0, 0, 0, 0);                        \
    acc1 = MFMA_B16(x1, BC8(Q5), acc1, 0, 0, 0);                        \
    acc2 = MFMA_B16(x1, BC8(Q6), acc2, 0, 0, 0);                        \
    acc3 = MFMA_B16(x1, BC8(Q7), acc3, 0, 0, 0);                        \
  } while (0)

  // software pipeline: 12 loads per step; vmcnt(12) = "the previous step's
  // 12 loads have retired" (in-order retirement), so the current step's
  // data is ready while the NEXT step's 12 stay in flight.
  // (explicit register lists — preprocessor splits args before expanding
  // macros, so no list-macro shorthand here)
  ISSUE(0, a00,a01,a02,a03, b00,b01,b02,b03,b04,b05,b06,b07);
  ISSUE(1, a10,a11,a12,a13, b10,b11,b12,b13,b14,b15,b16,b17);
  WAITN(12);
  COMPUTE(a00,a01,a02,a03, b00,b01,b02,b03,b04,b05,b06,b07);
  ISSUE(2, a00,a01,a02,a03, b00,b01,b02,b03,b04,b05,b06,b07);
  WAITN(12);
  COMPUTE(a10,a11,a12,a13, b10,b11,b12,b13,b14,b15,b16,b17);
  ISSUE(3, a10,a11,a12,a13, b10,b11,b12,b13,b14,b15,b16,b17);
  WAITN(12);
  COMPUTE(a00,a01,a02,a03, b00,b01,b02,b03,b04,b05,b06,b07);
  ISSUE(4, a00,a01,a02,a03, b00,b01,b02,b03,b04,b05,b06,b07);
  WAITN(12);
  COMPUTE(a10,a11,a12,a13, b10,b11,b12,b13,b14,b15,b16,b17);
  ISSUE(5, a10,a11,a12,a13, b10,b11,b12,b13,b14,b15,b16,b17);
  WAITN(12);
  COMPUTE(a00,a01,a02,a03, b00,b01,b02,b03,b04,b05,b06,b07);
  ISSUE(6, a00,a01,a02,a03, b00,b01,b02,b03,b04,b05,b06,b07);
  WAITN(12);
  COMPUTE(a10,a11,a12,a13, b10,b11,b12,b13,b14,b15,b16,b17);
  ISSUE(7, a10,a11,a12,a13, b10,b11,b12,b13,b14,b15,b16,b17);
  WAITN(12);
  COMPUTE(a00,a01,a02,a03, b00,b01,b02,b03,b04,b05,b06,b07);
  WAITN(0);
  COMPUTE(a10,a11,a12,a13, b10,b11,b12,b13,b14,b15,b16,b17);

#undef ISSUE
#undef WAITN
#undef COMPUTE

  // epilogue: C/D layout col=m16 -> channel, row=quad*4+r -> t-local
  const int t = t0 + wave*16 + quad*4;
  if (t < TDATA) {
    float* o = outp + t;
    *(float4*)(o + (size_t)(     m16)*TDATA) = *(float4*)&acc0;
    *(float4*)(o + (size_t)(16 + m16)*TDATA) = *(float4*)&acc1;
    *(float4*)(o + (size_t)(32 + m16)*TDATA) = *(float4*)&acc2;
    if (m16 < 12)
      *(float4*)(o + (size_t)(48 + m16)*TDATA) = *(float4*)&acc3;
  }
}

// ---------------------------------------------------------------------------
// K3: 201-tap causal FIR per (var,s), with the split-K reduction fused into
//     the LDS staging: E window = in_e + P1 + P2 + P3, I window = in_i.
// ---------------------------------------------------------------------------
__device__ __forceinline__ int swz(int i) { return i + (i >> 5); }

__global__ __launch_bounds__(256) void conv_kernel(
    const float* __restrict__ in_e, const float* __restrict__ P1,
    const float* __restrict__ P2,  const float* __restrict__ P3,
    const float* __restrict__ in_i,
    const float* __restrict__ kern, float* __restrict__ syn)
{
  __shared__ float Ee[2320];
  __shared__ float Ei[2320];
  const int ch = blockIdx.y;            // var*20 + s
  const int t0 = blockIdx.x * 2048;
  const int s  = ch % SUBS;
  const size_t off = (size_t)ch * TDATA;
  for (int i = threadIdx.x; i < 2248; i += 256) {
    const int g = t0 - 200 + i;
    float e = 0.f, ii = 0.f;
    if (g >= 0 && g < TDATA) {
      e = in_e[off + g] + P1[off + g] + P2[off + g] + P3[off + g];
      ii = in_i[off + g];
    }
    Ee[swz(i)] = e;
    Ei[swz(i)] = ii;
  }
  __syncthreads();
  const float* ke = kern + (size_t)(s*2    ) * TAPS;
  const float* ki = kern + (size_t)(s*2 + 1) * TAPS;
  const int tb = threadIdx.x * 8;
  float acc[8] = {0.f,0.f,0.f,0.f,0.f,0.f,0.f,0.f};
  float we[8], wi[8];
#pragma unroll
  for (int j = 0; j < 8; ++j) {
    we[j] = Ee[swz(tb + 200 + j)];
    wi[j] = Ei[swz(tb + 200 + j)];
  }
#pragma unroll 8
  for (int m = 0; m < TAPS; ++m) {
    const float k0 = ke[m];
    const float k1 = ki[m];
#pragma unroll
    for (int j = 0; j < 8; ++j)
      acc[j] = fmaf(we[j], k0, fmaf(wi[j], k1, acc[j]));
    if (m < TAPS - 1) {
#pragma unroll
      for (int j = 7; j > 0; --j) { we[j] = we[j-1]; wi[j] = wi[j-1]; }
      we[0] = Ee[swz(tb + 199 - m)];
      wi[0] = Ei[swz(tb + 199 - m)];
    }
  }
  const int t = t0 + tb;
  if (t < TDATA) {
    float* o = syn + off + t;
    *(float4*)(o    ) = make_float4(acc[0], acc[1], acc[2], acc[3]);
    *(float4*)(o + 4) = make_float4(acc[4], acc[5], acc[6], acc[7]);
  }
}

// ---------------------------------------------------------------------------
// K4: tanh tree combine -> V outputs
// ---------------------------------------------------------------------------
__global__ __launch_bounds__(256) void tree_kernel(
    const float* __restrict__ syn, const float* __restrict__ W_sub,
    const float* __restrict__ V_o, float* __restrict__ out)
{
  const int t = blockIdx.x * 256 + threadIdx.x;
  const int var = blockIdx.y;
  if (t >= TDATA) return;
  const float* sp = syn + (size_t)var * SUBS * TDATA + t;
  float so[SUBS];
#pragma unroll
  for (int s = SUBS - 1; s >= 0; --s) {
    float val = sp[(size_t)s * TDATA];
    const int c1 = 2*s + 1, c2 = 2*s + 2;
    if (c1 < SUBS) val += so[c1] * W_sub[c1];
    if (c2 < SUBS) val += so[c2] * W_sub[c2];
    so[s] = fast_tanh(val);
  }
  out[(size_t)var * TDATA + t] = so[0] * W_sub[0] + V_o[0];
}

extern "C" void kernel_launch(void* const* d_in, const int* in_sizes, int n_in,
                              void* d_out, int out_size, void* d_ws, size_t ws_size,
                              hipStream_t stream) {
  const float* S_e     = (const float*)d_in[0];
  const float* S_i     = (const float*)d_in[1];
  const float* u       = (const float*)d_in[2];
  const float* v       = (const float*)d_in[3];
  const float* W_syn   = (const float*)d_in[4];
  const float* Tau_syn = (const float*)d_in[5];
  const float* Delta   = (const float*)d_in[6];
  const float* W_sub   = (const float*)d_in[7];
  const float* V_o     = (const float*)d_in[8];
  const float* C_log   = (const float*)d_in[10];   // d_in[9] = Theta, unused
  float* out = (float*)d_out;
  char* ws = (char*)d_ws;
  unsigned short* wge = (unsigned short*)(ws + WGE_OFF);
  unsigned short* wgi = (unsigned short*)(ws + WGI_OFF);
  float* kern = (float*)(ws + KERN_OFF);
  float* in_e = (float*)(ws + INE_OFF);
  float* in_i = (float*)(ws + INI_OFF);
  float* P1   = (float*)(ws + P1_OFF);
  float* P2   = (float*)(ws + P2_OFF);
  float* P3   = (float*)(ws + P3_OFF);
  float* syn  = (float*)(ws + SYN_OFF);

  prep_kernel<<<dim3(11), dim3(256), 0, stream>>>(u, v, C_log, W_syn, Tau_syn,
                                                  Delta, out, wge, wgi, kern);
  gemm_kernel<<<dim3(313, 5), dim3(256), 0, stream>>>(
      S_e, S_i, wge, wgi, in_e, in_i, P1, P2, P3);
  conv_kernel<<<dim3(10, 60), dim3(256), 0, stream>>>(in_e, P1, P2, P3, in_i,
                                                      kern, syn);
  tree_kernel<<<dim3(79, 3), dim3(256), 0, stream>>>(syn, W_sub, V_o, out);
}